// Round 10
// baseline (76.435 us; speedup 1.0000x reference)
//
#include <hip/hip_runtime.h>

typedef float f32x4 __attribute__((ext_vector_type(4)));
typedef __bf16 bf16x8 __attribute__((ext_vector_type(8)));

#define K_FEAT 8192
#define N_FEAT 8192
#define M_TOK 64
#define TILES_N 512
#define TILES_K 512
#define WROW 40         /* 32 k + 8 pad ushorts; 80 B rows (16 B-aligned reads) */
#define LG_KSPLIT 3
#define KSPLIT 8
#define NSTEP 32        /* 64 k-tiles per split / 2 per step */

__device__ __forceinline__ unsigned short f2bf(float f) {
    unsigned int u = __builtin_bit_cast(unsigned int, f);
    u = (u + 0x7FFFu + ((u >> 16) & 1u)) >> 16;
    return (unsigned short)u;
}
__device__ __forceinline__ float bf2f(unsigned short h) {
    return __builtin_bit_cast(float, (unsigned int)h << 16);
}

// xb[m][k] = bf16(x[m][k] * su[k])
__global__ void __launch_bounds__(256)
prep_x_kernel(const float* __restrict__ x, const float* __restrict__ su,
              unsigned short* __restrict__ xb)
{
    int i = blockIdx.x * 256 + threadIdx.x;          // float4 index over [64][8192]
    const float4* x4 = (const float4*)x;
    const float4* su4 = (const float4*)su;
    float4 xv = x4[i];
    float4 s4 = su4[i & (K_FEAT / 4 - 1)];
    ushort4 o;
    o.x = f2bf(xv.x * s4.x);
    o.y = f2bf(xv.y * s4.y);
    o.z = f2bf(xv.z * s4.z);
    o.w = f2bf(xv.w * s4.w);
    ((ushort4*)xb)[i] = o;
}

// Barrier-free main kernel: waves split the block's 64 cols by n (16 each).
// B-tiles are wave-private (staged+consumed by the same wave; LDS ops from a
// single wave execute in order, so no sync is needed anywhere in the loop).
__global__ void __launch_bounds__(256)
trellis_main(const int* __restrict__ packed,
             const float* __restrict__ scales,
             const float* __restrict__ sv,
             const float* __restrict__ grid,
             const unsigned short* __restrict__ xb,
             unsigned short* __restrict__ partials)
{
    __shared__ unsigned int table[256];
    __shared__ unsigned short wlds[4][2][16 * WROW];  // [wave][dbuf][16n x 32k+pad]
    __shared__ float slds[8 * 64];                    // 8 scale-blocks x 64 cols

    const int tid = threadIdx.x;
    const int bid = blockIdx.x;
    const int s = bid & (KSPLIT - 1);
    const int ng = bid >> LG_KSPLIT;                 // 0..127 (64-col groups)
    const int col0 = ng * 64;
    const int nt0 = ng * 4;
    const int ktile0 = s * (TILES_K / KSPLIT);

    const int wn = tid >> 6;         // wave's n-tile (0..3)
    const int lane = tid & 63;
    const int l5 = lane >> 5;        // which of the 2 k-tiles this lane stages
    const int l32 = lane & 31;
    const int q = l32 >> 1;          // k-row within tile (0..15)
    const int r = l32 & 1;           // n-octet (0..1)
    const int ln15 = lane & 15;
    const int kgrp = (lane >> 4) * 8;

    // packed: lane's uint4 = 4 payload bytes = 8 consecutive n at k-row q
    const int* pb = packed
        + ((size_t)(ktile0 + l5) * TILES_N + (nt0 + wn)) * 128 + 4 * l32;
    const int stepstride = 2 * TILES_N * 128;        // advance 2 k-tiles

    // LDS offsets (ushort units)
    const int wo = (8 * r) * WROW + l5 * 16 + q;     // write base (rows 8r..8r+7)
    const int ro = ln15 * WROW + kgrp;               // read: row n=ln15, k 8-chunk
    unsigned short* buf0 = &wlds[wn][0][0];
    unsigned short* buf1 = &wlds[wn][1][0];

    // A: lane reads 8 k-contig bf16 of row m = mi*16 + ln15
    const unsigned short* xbase = xb + (size_t)ln15 * K_FEAT + ktile0 * 16 + kgrp;

    // pair table: byte -> (bf16(grid[lo]), bf16(grid[hi])) = 2 n-consecutive weights
    {
        float lo = grid[tid & 15];
        float hi = grid[(tid >> 4) & 15];
        table[tid] = (unsigned int)f2bf(lo) | ((unsigned int)f2bf(hi) << 16);
    }
    // scales for this block's k-range: 8 blocks x 64 cols
    {
        const int kb0 = s * 8;
        slds[tid]       = scales[(size_t)(kb0 + (tid >> 6)) * N_FEAT + col0 + (tid & 63)];
        slds[tid + 256] = scales[(size_t)(kb0 + 4 + (tid >> 6)) * N_FEAT + col0 + (tid & 63)];
    }
    __syncthreads();   // table + slds ready — the ONLY barrier in this kernel

    // ---- prologue: stage tile 0; tile 1 + A(0) in flight ----
    uint4 pk0    = *(const uint4*)(pb);
    uint4 pk_nxt = *(const uint4*)(pb + stepstride);
    uint4 ac0 = *(const uint4*)(xbase);
    uint4 ac1 = *(const uint4*)(xbase + 16 * K_FEAT);
    uint4 ac2 = *(const uint4*)(xbase + 32 * K_FEAT);
    uint4 ac3 = *(const uint4*)(xbase + 48 * K_FEAT);
    {
        uint4 wq;
        wq.x = table[pk0.x & 255];
        wq.y = table[pk0.y & 255];
        wq.z = table[pk0.z & 255];
        wq.w = table[pk0.w & 255];
        unsigned short* wp = buf0 + wo;
        wp[0 * WROW] = (unsigned short)(wq.x);
        wp[1 * WROW] = (unsigned short)(wq.x >> 16);
        wp[2 * WROW] = (unsigned short)(wq.y);
        wp[3 * WROW] = (unsigned short)(wq.y >> 16);
        wp[4 * WROW] = (unsigned short)(wq.z);
        wp[5 * WROW] = (unsigned short)(wq.z >> 16);
        wp[6 * WROW] = (unsigned short)(wq.w);
        wp[7 * WROW] = (unsigned short)(wq.w >> 16);
    }

    f32x4 acc[4], acc2[4];
#pragma unroll
    for (int d = 0; d < 4; ++d)
#pragma unroll
        for (int j = 0; j < 4; ++j) { acc[d][j] = 0.f; acc2[d][j] = 0.f; }

    unsigned short* brd = buf0;      // holds tile t
    unsigned short* bw  = buf1;      // receives tile t+1

    for (int t = 0; t < NSTEP; ++t) {
        // issue loads for step t+2 (packed) and t+1 (A); tails clamp (L2 hit)
        const int t2 = (t + 2 < NSTEP) ? t + 2 : NSTEP - 1;
        uint4 pk_fut = *(const uint4*)(pb + (size_t)t2 * stepstride);
        const int t1 = (t + 1 < NSTEP) ? t + 1 : NSTEP - 1;
        const unsigned short* xn = xbase + t1 * 32;
        uint4 an0 = *(const uint4*)(xn);
        uint4 an1 = *(const uint4*)(xn + 16 * K_FEAT);
        uint4 an2 = *(const uint4*)(xn + 32 * K_FEAT);
        uint4 an3 = *(const uint4*)(xn + 48 * K_FEAT);

        // stage tile t+1 into bw (zero-repack: table dwords ARE the bf16 pairs)
        {
            uint4 wq;
            wq.x = table[pk_nxt.x & 255];
            wq.y = table[pk_nxt.y & 255];
            wq.z = table[pk_nxt.z & 255];
            wq.w = table[pk_nxt.w & 255];
            unsigned short* wp = bw + wo;
            wp[0 * WROW] = (unsigned short)(wq.x);
            wp[1 * WROW] = (unsigned short)(wq.x >> 16);
            wp[2 * WROW] = (unsigned short)(wq.y);
            wp[3 * WROW] = (unsigned short)(wq.y >> 16);
            wp[4 * WROW] = (unsigned short)(wq.z);
            wp[5 * WROW] = (unsigned short)(wq.z >> 16);
            wp[6 * WROW] = (unsigned short)(wq.w);
            wp[7 * WROW] = (unsigned short)(wq.w >> 16);
        }

        // consume tile t from brd: ONE b128 read (n=ln15, k 0..31), 4 MFMAs
        bf16x8 bfrag = *(const bf16x8*)(brd + ro);
        acc2[0] = __builtin_amdgcn_mfma_f32_16x16x32_bf16(
            __builtin_bit_cast(bf16x8, ac0), bfrag, acc2[0], 0, 0, 0);
        acc2[1] = __builtin_amdgcn_mfma_f32_16x16x32_bf16(
            __builtin_bit_cast(bf16x8, ac1), bfrag, acc2[1], 0, 0, 0);
        acc2[2] = __builtin_amdgcn_mfma_f32_16x16x32_bf16(
            __builtin_bit_cast(bf16x8, ac2), bfrag, acc2[2], 0, 0, 0);
        acc2[3] = __builtin_amdgcn_mfma_f32_16x16x32_bf16(
            __builtin_bit_cast(bf16x8, ac3), bfrag, acc2[3], 0, 0, 0);

        // every 4 steps (= 128 k rows = one scale block): fold scale into acc.
        // All 4 m-tiles share one n-column scale.
        if ((t & 3) == 3) {
            float sc = slds[(t >> 2) * 64 + wn * 16 + ln15];
#pragma unroll
            for (int d = 0; d < 4; ++d) {
                acc[d] += acc2[d] * sc;
#pragma unroll
                for (int j = 0; j < 4; ++j) acc2[d][j] = 0.f;
            }
        }

        pk_nxt = pk_fut;
        ac0 = an0; ac1 = an1; ac2 = an2; ac3 = an3;
        unsigned short* tmp = brd; brd = bw; bw = tmp;
    }

    // epilogue: apply sv, write bf16 partial [s][m][n]; n = col0+wn*16+ln15
    unsigned short* pout = partials + (size_t)s * (M_TOK * N_FEAT);
    const int n = col0 + wn * 16 + ln15;
    const float svv = sv[n];
    const int rbase = (lane >> 4) * 4;
#pragma unroll
    for (int d = 0; d < 4; ++d) {
#pragma unroll
        for (int j = 0; j < 4; ++j) {
            int m = d * 16 + rbase + j;
            pout[(size_t)m * N_FEAT + n] = f2bf(acc[d][j] * svv);
        }
    }
}

__global__ void __launch_bounds__(256)
reduce_kernel(const unsigned short* __restrict__ partials, float* __restrict__ out)
{
    int i = blockIdx.x * 256 + threadIdx.x;          // ushort8 group index (65536 total)
    const uint4* p = (const uint4*)partials;         // 8 bf16 per uint4
    float acc[8];
    for (int e = 0; e < 8; ++e) acc[e] = 0.f;
    for (int k = 0; k < KSPLIT; ++k) {
        uint4 v = p[(size_t)k * (M_TOK * N_FEAT / 8) + i];
        unsigned int uu[4] = {v.x, v.y, v.z, v.w};
        for (int q = 0; q < 4; ++q) {
            acc[2 * q]     += bf2f((unsigned short)(uu[q] & 0xFFFFu));
            acc[2 * q + 1] += bf2f((unsigned short)(uu[q] >> 16));
        }
    }
    float4 o0 = make_float4(acc[0], acc[1], acc[2], acc[3]);
    float4 o1 = make_float4(acc[4], acc[5], acc[6], acc[7]);
    ((float4*)out)[2 * i]     = o0;
    ((float4*)out)[2 * i + 1] = o1;
}

extern "C" void kernel_launch(void* const* d_in, const int* in_sizes, int n_in,
                              void* d_out, int out_size, void* d_ws, size_t ws_size,
                              hipStream_t stream)
{
    const float* x      = (const float*)d_in[0];
    const int*   packed = (const int*)d_in[1];
    const float* scales = (const float*)d_in[2];
    const float* su     = (const float*)d_in[3];
    const float* sv     = (const float*)d_in[4];
    const float* grid   = (const float*)d_in[5];
    float* out = (float*)d_out;

    unsigned short* xb = (unsigned short*)d_ws;
    const size_t xb_bytes = (size_t)M_TOK * K_FEAT * 2;   // 1 MB
    unsigned short* partials = (unsigned short*)((char*)d_ws + xb_bytes);

    prep_x_kernel<<<(M_TOK * K_FEAT / 4) / 256, 256, 0, stream>>>(x, su, xb);
    trellis_main<<<(N_FEAT / 64) * KSPLIT, 256, 0, stream>>>(
        packed, scales, sv, grid, xb, partials);
    reduce_kernel<<<(M_TOK * N_FEAT / 8) / 256, 256, 0, stream>>>(partials, out);
}

// Round 11
// 38.663 us; speedup vs baseline: 1.9769x; 1.9769x over previous
//
#include <hip/hip_runtime.h>

typedef float f32x4 __attribute__((ext_vector_type(4)));
typedef __bf16 bf16x8 __attribute__((ext_vector_type(8)));

#define K_FEAT 8192
#define N_FEAT 8192
#define M_TOK 64
#define TILES_N 512
#define TILES_K 512
#define WROWSTRIDE 40   /* 32 k + 8 pad, in ushort units */
#define LG_KSPLIT 3
#define KSPLIT 8
#define NSTEP 32        /* (TILES_K/KSPLIT) tiles / 2 per step */

__device__ __forceinline__ unsigned short f2bf(float f) {
    unsigned int u = __builtin_bit_cast(unsigned int, f);
    u = (u + 0x7FFFu + ((u >> 16) & 1u)) >> 16;
    return (unsigned short)u;
}
__device__ __forceinline__ float bf2f(unsigned short h) {
    return __builtin_bit_cast(float, (unsigned int)h << 16);
}

// xb[m][k] = bf16(x[m][k] * su[k])
__global__ void __launch_bounds__(256)
prep_x_kernel(const float* __restrict__ x, const float* __restrict__ su,
              unsigned short* __restrict__ xb)
{
    int i = blockIdx.x * 256 + threadIdx.x;          // float4 index over [64][8192]
    const float4* x4 = (const float4*)x;
    const float4* su4 = (const float4*)su;
    float4 xv = x4[i];
    float4 s4 = su4[i & (K_FEAT / 4 - 1)];
    ushort4 o;
    o.x = f2bf(xv.x * s4.x);
    o.y = f2bf(xv.y * s4.y);
    o.z = f2bf(xv.z * s4.z);
    o.w = f2bf(xv.w * s4.w);
    ((ushort4*)xb)[i] = o;
}

__global__ void __launch_bounds__(256)
trellis_main(const int* __restrict__ packed,
             const float* __restrict__ scales,
             const float* __restrict__ sv,
             const float* __restrict__ grid,
             const unsigned short* __restrict__ xb,
             unsigned short* __restrict__ partials)
{
    __shared__ unsigned int table[256];
    __shared__ unsigned short wlds[3][64 * WROWSTRIDE];  // 3-deep rotation
    __shared__ float slds[8 * 64];   // 8 scale-blocks x 64 cols for this block

    const int tid = threadIdx.x;
    const int bid = blockIdx.x;
    const int s = bid & (KSPLIT - 1);
    const int ng = bid >> LG_KSPLIT;                 // 0..127 (64-col groups)
    const int col0 = ng * 64;
    const int nt0 = ng * 4;
    const int ktile0 = s * (TILES_K / KSPLIT);

    // ---- staging coords: 8 tiles/step = 2 kt x 4 nt; 32 threads per tile ----
    const int tau = tid >> 5;
    const int dkt = tau >> 2;        // 0..1
    const int dnt_s = tau & 3;       // 0..3
    const int w = tid & 31;
    const int c = w & 7;             // n-pair: rows 2c, 2c+1
    const int g = w >> 3;            // k-group: k = 4g..4g+3

    const int* pb = packed
        + ((size_t)(ktile0 + dkt) * TILES_N + (nt0 + dnt_s)) * 128 + c + 32 * g;
    const int stepstride = 2 * TILES_N * 128;        // advance 2 k-tiles

    // staging write offsets within a buffer (ushort units)
    const int nrow = dnt_s * 16 + 2 * c;
    const int koff = dkt * 16 + 4 * g;
    const int wof = nrow * WROWSTRIDE + koff;

    // ---- compute coords ----
    const int wave = tid >> 6;       // m-tile 0..3
    const int lane = tid & 63;
    const int ln15 = lane & 15;
    const int kgrp = (lane >> 4) * 8;
    const unsigned short* xrow = xb + (size_t)(wave * 16 + ln15) * K_FEAT;

    // pair table: byte -> (bf16(grid[lo]), bf16(grid[hi]))
    {
        float lo = grid[tid & 15];
        float hi = grid[(tid >> 4) & 15];
        table[tid] = (unsigned int)f2bf(lo) | ((unsigned int)f2bf(hi) << 16);
    }
    // scales for this block's k-range: 8 blocks x 64 cols
    {
        const int kb0 = s * 8;
        slds[tid]       = scales[(size_t)(kb0 + (tid >> 6)) * N_FEAT + col0 + (tid & 63)];
        slds[tid + 256] = scales[(size_t)(kb0 + 4 + (tid >> 6)) * N_FEAT + col0 + (tid & 63)];
    }

    // prologue: packed ints for tile 0, A-frag for tile 0
    int ld0 = pb[0], ld1 = pb[8], ld2 = pb[16], ld3 = pb[24];
    uint4 ra = *(const uint4*)(xrow + ktile0 * 16 + kgrp);

    f32x4 acc[4], acc2[4];
    for (int d = 0; d < 4; ++d)
        for (int j = 0; j < 4; ++j) { acc[d][j] = 0.f; acc2[d][j] = 0.f; }

    __syncthreads();   // table + slds ready

    // stage tile 0 -> wlds[0]
    {
        unsigned int t0 = table[ld0 & 255];
        unsigned int t1 = table[ld1 & 255];
        unsigned int t2 = table[ld2 & 255];
        unsigned int t3 = table[ld3 & 255];
        unsigned int w0 = (t0 & 0xFFFFu) | (t1 << 16);
        unsigned int w1 = (t2 & 0xFFFFu) | (t3 << 16);
        unsigned int w2 = (t0 >> 16)     | (t1 & 0xFFFF0000u);
        unsigned int w3 = (t2 >> 16)     | (t3 & 0xFFFF0000u);
        unsigned short* dst = &wlds[0][wof];
        *(uint2*)dst = make_uint2(w0, w1);
        *(uint2*)(dst + WROWSTRIDE) = make_uint2(w2, w3);
    }
    // load tile 1 packed ints (in flight across the barrier)
    {
        const int* p1 = pb + stepstride;
        ld0 = p1[0]; ld1 = p1[8]; ld2 = p1[16]; ld3 = p1[24];
    }

    __builtin_amdgcn_sched_barrier(0);
    asm volatile("s_waitcnt lgkmcnt(0)" ::: "memory");
    __builtin_amdgcn_s_barrier();
    __builtin_amdgcn_sched_barrier(0);

    // issue B-fragment reads for tile 0 (latency hidden under iter 0's staging)
    bf16x8 fb0, fb1, fb2, fb3;
    {
        const unsigned short* rb = &wlds[0][0];
        fb0 = *(const bf16x8*)(rb + (0 * 16 + ln15) * WROWSTRIDE + kgrp);
        fb1 = *(const bf16x8*)(rb + (1 * 16 + ln15) * WROWSTRIDE + kgrp);
        fb2 = *(const bf16x8*)(rb + (2 * 16 + ln15) * WROWSTRIDE + kgrp);
        fb3 = *(const bf16x8*)(rb + (3 * 16 + ln15) * WROWSTRIDE + kgrp);
    }

    for (int t = 0; t < NSTEP; ++t) {
        // issue packed loads for tile t+2 and A for tile t+1 (clamped tails)
        const int tc = (t + 2 < NSTEP) ? (t + 2) : (NSTEP - 1);
        const int* pn = pb + (size_t)tc * stepstride;
        int n0 = pn[0], n1 = pn[8], n2 = pn[16], n3 = pn[24];
        const int t1i = (t + 1 < NSTEP) ? (t + 1) : (NSTEP - 1);
        uint4 ran = *(const uint4*)(xrow + ktile0 * 16 + t1i * 32 + kgrp);

        unsigned short* wb = &wlds[(t + 1) % 3][0];

        if (t + 1 < NSTEP) {
            // stage tile t+1 -> wb (overlaps the in-flight fb reads of tile t)
            unsigned int t0 = table[ld0 & 255];
            unsigned int t1 = table[ld1 & 255];
            unsigned int t2 = table[ld2 & 255];
            unsigned int t3 = table[ld3 & 255];
            unsigned int w0 = (t0 & 0xFFFFu) | (t1 << 16);
            unsigned int w1 = (t2 & 0xFFFFu) | (t3 << 16);
            unsigned int w2 = (t0 >> 16)     | (t1 & 0xFFFF0000u);
            unsigned int w3 = (t2 >> 16)     | (t3 & 0xFFFF0000u);
            unsigned short* dst = wb + wof;
            *(uint2*)dst = make_uint2(w0, w1);
            *(uint2*)(dst + WROWSTRIDE) = make_uint2(w2, w3);
        }

        // MFMA on tile t's fragments (reads issued last iter -> latency covered)
        bf16x8 aa = __builtin_bit_cast(bf16x8, ra);
        acc2[0] = __builtin_amdgcn_mfma_f32_16x16x32_bf16(aa, fb0, acc2[0], 0, 0, 0);
        acc2[1] = __builtin_amdgcn_mfma_f32_16x16x32_bf16(aa, fb1, acc2[1], 0, 0, 0);
        acc2[2] = __builtin_amdgcn_mfma_f32_16x16x32_bf16(aa, fb2, acc2[2], 0, 0, 0);
        acc2[3] = __builtin_amdgcn_mfma_f32_16x16x32_bf16(aa, fb3, acc2[3], 0, 0, 0);

        // every 4 steps (= 128 k rows = one scale block): fold scales into acc
        if ((t & 3) == 3) {
            const float* srow = slds + (t >> 2) * 64 + ln15;
            for (int d = 0; d < 4; ++d) {
                float sc = srow[d * 16];
                acc[d] += acc2[d] * sc;
                for (int j = 0; j < 4; ++j) acc2[d][j] = 0.f;
            }
        }

        if (t + 1 < NSTEP) {
            // raw barrier: drain LDS (stage writes), NOT in-flight global loads
            __builtin_amdgcn_sched_barrier(0);
            asm volatile("s_waitcnt lgkmcnt(0)" ::: "memory");
            __builtin_amdgcn_s_barrier();
            __builtin_amdgcn_sched_barrier(0);

            // issue B-fragment reads for tile t+1 (consumed next iteration)
            fb0 = *(const bf16x8*)(wb + (0 * 16 + ln15) * WROWSTRIDE + kgrp);
            fb1 = *(const bf16x8*)(wb + (1 * 16 + ln15) * WROWSTRIDE + kgrp);
            fb2 = *(const bf16x8*)(wb + (2 * 16 + ln15) * WROWSTRIDE + kgrp);
            fb3 = *(const bf16x8*)(wb + (3 * 16 + ln15) * WROWSTRIDE + kgrp);
        }

        ra = ran;
        ld0 = n0; ld1 = n1; ld2 = n2; ld3 = n3;
    }

    // epilogue: apply sv, write bf16 partial [s][m][n]
    unsigned short* pout = partials + (size_t)s * (M_TOK * N_FEAT);
    const int rbase = (lane >> 4) * 4;
    for (int d = 0; d < 4; ++d) {
        int n = col0 + d * 16 + ln15;
        float svv = sv[n];
        for (int j = 0; j < 4; ++j) {
            int m = wave * 16 + rbase + j;
            pout[(size_t)m * N_FEAT + n] = f2bf(acc[d][j] * svv);
        }
    }
}

__global__ void __launch_bounds__(256)
reduce_kernel(const unsigned short* __restrict__ partials, float* __restrict__ out)
{
    int i = blockIdx.x * 256 + threadIdx.x;          // ushort8 group index (65536 total)
    const uint4* p = (const uint4*)partials;         // 8 bf16 per uint4
    float acc[8];
    for (int e = 0; e < 8; ++e) acc[e] = 0.f;
    for (int k = 0; k < KSPLIT; ++k) {
        uint4 v = p[(size_t)k * (M_TOK * N_FEAT / 8) + i];
        unsigned int uu[4] = {v.x, v.y, v.z, v.w};
        for (int q = 0; q < 4; ++q) {
            acc[2 * q]     += bf2f((unsigned short)(uu[q] & 0xFFFFu));
            acc[2 * q + 1] += bf2f((unsigned short)(uu[q] >> 16));
        }
    }
    float4 o0 = make_float4(acc[0], acc[1], acc[2], acc[3]);
    float4 o1 = make_float4(acc[4], acc[5], acc[6], acc[7]);
    ((float4*)out)[2 * i]     = o0;
    ((float4*)out)[2 * i + 1] = o1;
}

extern "C" void kernel_launch(void* const* d_in, const int* in_sizes, int n_in,
                              void* d_out, int out_size, void* d_ws, size_t ws_size,
                              hipStream_t stream)
{
    const float* x      = (const float*)d_in[0];
    const int*   packed = (const int*)d_in[1];
    const float* scales = (const float*)d_in[2];
    const float* su     = (const float*)d_in[3];
    const float* sv     = (const float*)d_in[4];
    const float* grid   = (const float*)d_in[5];
    float* out = (float*)d_out;

    unsigned short* xb = (unsigned short*)d_ws;
    const size_t xb_bytes = (size_t)M_TOK * K_FEAT * 2;   // 1 MB
    unsigned short* partials = (unsigned short*)((char*)d_ws + xb_bytes);

    prep_x_kernel<<<(M_TOK * K_FEAT / 4) / 256, 256, 0, stream>>>(x, su, xb);
    trellis_main<<<(N_FEAT / 64) * KSPLIT, 256, 0, stream>>>(
        packed, scales, sv, grid, xb, partials);
    reduce_kernel<<<(M_TOK * N_FEAT / 8) / 256, 256, 0, stream>>>(partials, out);
}